// Round 6
// baseline (373.467 us; speedup 1.0000x reference)
//
#include <hip/hip_runtime.h>
#include <hip/hip_bf16.h>

#define N_NODES 10000
#define SEQ_T 12
#define IN_CH 16
#define HID 64
#define N_EDGES 160000

typedef __attribute__((ext_vector_type(8))) short short8;
typedef __attribute__((ext_vector_type(4))) float floatx4;

// ---- helpers ----
__device__ __forceinline__ float sigmf(float x){ return 1.0f / (1.0f + __expf(-x)); }
__device__ __forceinline__ float tanh_fast(float x){ return 1.0f - 2.0f / (1.0f + __expf(2.0f * x)); }
__device__ __forceinline__ float bf2f(unsigned short u){
  union { unsigned int i; float f; } c; c.i = ((unsigned int)u) << 16; return c.f;
}
__device__ __forceinline__ unsigned short f2bf(float f){
  union { float f; unsigned int u; } c; c.f = f;
  unsigned int u = c.u;
  return (unsigned short)((u + 0x7FFFu + ((u >> 16) & 1u)) >> 16);   // RNE
}

// wb (fp32 param block) float offsets:
//   49152 b_ih0 192 | 49344 b_hh0 192 | 49536 b_ih1 192 | 49728 b_hh1 192
//   49920 gcn_w 1024 | 50944 gcn_b 64
//   51008 attn_w 64 | 51072 attn_b 1 | 51073 fc_w 64 | 51137 fc_b 1
// wF (bf16): 4 matrices (l0ih,l0hh,l1ih,l1hh) x [kt(2)][jt(12)][lane(64)][e(8)]
//   B-frag element = W[j = (lane&15)+16*jt][k = (lane>>4)*8 + e + 32*kt]

// ---- param prep + edge count (cnt pre-zeroed by memset) ----
__global__ void k_prep(const float* __restrict__ gcn_w,
                       const float* __restrict__ gcn_b,
                       const float* __restrict__ wih0,
                       const float* __restrict__ whh0,
                       const float* __restrict__ bih0,
                       const float* __restrict__ bhh0,
                       const float* __restrict__ wih1,
                       const float* __restrict__ whh1,
                       const float* __restrict__ bih1,
                       const float* __restrict__ bhh1,
                       const float* __restrict__ attn_w,
                       const float* __restrict__ attn_b,
                       const float* __restrict__ fc_w,
                       const float* __restrict__ fc_b,
                       const int* __restrict__ ei,
                       float* __restrict__ wb, unsigned short* __restrict__ wF,
                       int* __restrict__ cnt){
  int p = blockIdx.y;
  int i = blockIdx.x * 256 + threadIdx.x;
  if (p == 14){                               // in-degree count over dst
    if (i < N_EDGES) atomicAdd(&cnt[ei[N_EDGES + i]], 1);
    return;
  }
  const float* srcs[14] = {wih0, whh0, wih1, whh1, bih0, bhh0, bih1, bhh1,
                           gcn_w, gcn_b, attn_w, attn_b, fc_w, fc_b};
  const int sizes[14] = {12288,12288,12288,12288,192,192,192,192,1024,64,64,1,64,1};
  const int dsts[14]  = {0,0,0,0,49152,49344,49536,49728,49920,50944,51008,51072,51073,51137};
  if (i >= sizes[p]) return;
  if (p < 4){
    // frag swizzle: i = ((kt*12+jt)*64 + l)*8 + e
    int e = i & 7, l = (i >> 3) & 63, jk = i >> 9;
    int kt = jk / 12, jt = jk - kt * 12;
    int j = (l & 15) + 16 * jt;
    int k = ((l >> 4) * 8) + e + 32 * kt;
    wF[p * 12288 + i] = f2bf(srcs[p][j * 64 + k]);
  } else {
    wb[dsts[p] + i] = srcs[p][i];
  }
}

// ---- exclusive scan -> row offsets; dis = rsqrt(deg); cursor=row (aliases cnt) ----
__global__ __launch_bounds__(1024) void k_scan(int* __restrict__ cnt_cursor,
                                               int* __restrict__ row,
                                               float* __restrict__ dis){
  __shared__ int sums[1024];
  const int CH = 10;
  int tid = threadIdx.x;
  int base = tid * CH;
  int local[CH]; int s = 0;
  #pragma unroll
  for (int i = 0; i < CH; ++i){
    int idx = base + i;
    int v = (idx < N_NODES) ? cnt_cursor[idx] : 0;
    local[i] = s;
    s += v;
    if (idx < N_NODES) dis[idx] = rsqrtf((float)v + 1.0f);
  }
  sums[tid] = s;
  __syncthreads();
  for (int off = 1; off < 1024; off <<= 1){
    int v = (tid >= off) ? sums[tid - off] : 0;
    __syncthreads();
    sums[tid] += v;
    __syncthreads();
  }
  int excl = sums[tid] - s;
  #pragma unroll
  for (int i = 0; i < CH; ++i){
    int idx = base + i;
    if (idx < N_NODES){
      int r = excl + local[i];
      row[idx] = r;
      cnt_cursor[idx] = r;
    }
  }
  if (tid == 1023) row[N_NODES] = sums[1023];
}

// ---- CSR fill: (src, dst, w) packed per edge ----
__global__ void k_fill(const int* __restrict__ ei, int* __restrict__ cursor,
                       const float* __restrict__ dis, int4* __restrict__ csr){
  int e = blockIdx.x * 256 + threadIdx.x;
  if (e >= N_EDGES) return;
  int s = ei[e], d = ei[N_EDGES + e];
  int pos = atomicAdd(&cursor[d], 1);
  csr[pos] = make_int4(s, d, __float_as_int(dis[s] * dis[d]), 0);
}

// ---- fused gather (edge-parallel, LDS accum) + GCN matmul + relu -> goutF ----
// block = (dst chunk of 256, t). 16 groups x 16 ch stream the contiguous CSR span.
// goutF layout: [t][mt_g(625)][kt(2)][lane(64)][e(8)] bf16,
//   element = act[node = mt_g*16 + (lane&15)][k = kt*32 + (lane>>4)*8 + e]
#define DCH 256
__global__ __launch_bounds__(256) void k_gather_gcn(
    const float* __restrict__ x, const int* __restrict__ row,
    const int4* __restrict__ csr, const float* __restrict__ dis,
    const float* __restrict__ wb, unsigned short* __restrict__ goutF){
  __shared__ float acc[DCH * 17];          // [d][ch], pad 17 vs bank conflicts
  __shared__ float smw[IN_CH * HID];
  __shared__ float smb[HID];
  const int tid = threadIdx.x;
  const int t = blockIdx.y;
  const int d0 = blockIdx.x * DCH;
  const int dend = (d0 + DCH < N_NODES) ? d0 + DCH : N_NODES;
  for (int i = tid; i < IN_CH * HID; i += 256) smw[i] = wb[49920 + i];
  if (tid < HID) smb[tid] = wb[50944 + tid];
  // phase 0: self-loop init
  for (int i = tid; i < DCH * 16; i += 256){
    int d = i >> 4, ch = i & 15;
    float v = 0.0f;
    if (d0 + d < N_NODES){
      float dd = dis[d0 + d];
      v = dd * dd * x[((size_t)t * N_NODES + d0 + d) * IN_CH + ch];
    }
    acc[d * 17 + ch] = v;
  }
  __syncthreads();
  // phase 1: edge-parallel accumulate (iterations independent -> pipelined)
  const int grp = tid >> 4, ch = tid & 15;
  const int e_end = row[dend];
  #pragma unroll 4
  for (int e = row[d0] + grp; e < e_end; e += 16){
    int4 c = csr[e];                       // (src, dst, w) broadcast in group
    float v = x[((size_t)t * N_NODES + c.x) * IN_CH + ch];
    atomicAdd(&acc[(c.y - d0) * 17 + ch], __int_as_float(c.z) * v);
  }
  __syncthreads();
  // phase 2: per-thread dst: 16->64 matmul + bias + relu + frag store
  int d = d0 + tid;
  if (d < N_NODES){
    float v[16];
    #pragma unroll
    for (int f = 0; f < 16; ++f) v[f] = acc[tid * 17 + f];
    float o[HID];
    #pragma unroll
    for (int h = 0; h < HID; ++h) o[h] = smb[h];
    #pragma unroll
    for (int f = 0; f < 16; ++f)
      #pragma unroll
      for (int h = 0; h < HID; ++h) o[h] = fmaf(v[f], smw[f * HID + h], o[h]);
    #pragma unroll
    for (int hb8 = 0; hb8 < 8; ++hb8){
      unsigned int pk[4];
      #pragma unroll
      for (int pairi = 0; pairi < 4; ++pairi){
        unsigned int lo = f2bf(fmaxf(o[hb8 * 8 + pairi * 2], 0.0f));
        unsigned int hi = f2bf(fmaxf(o[hb8 * 8 + pairi * 2 + 1], 0.0f));
        pk[pairi] = lo | (hi << 16);
      }
      size_t base = ((((size_t)t * 625 + (d >> 4)) * 2 + (hb8 >> 2)) * 64
                     + (d & 15) + 16 * (hb8 & 3)) * 8;
      *(uint4*)(goutF + base) = make_uint4(pk[0], pk[1], pk[2], pk[3]);
    }
  }
}

// ---- fused 2-layer GRU on MFMA + attention/FC/residual epilogue. ----
// block = 32 nodes (2 m-tiles), 4 waves; wave w owns j-tiles {w, w+4, w+8}.
// 313 blocks -> every CU covered, 2 blocks/CU overlap MFMA with gate VALU.
__global__ __launch_bounds__(256, 1) void k_gru(
    const unsigned short* __restrict__ goutF, const unsigned short* __restrict__ wF,
    const float* __restrict__ wb, unsigned short* __restrict__ h0F,
    const float* __restrict__ x, float* __restrict__ out){
  __shared__ unsigned short hF[2 * 2 * 64 * 8];   // [mt][kt][lane][e], bf16
  __shared__ float scdc[SEQ_T][2][32];            // [t][sc/dc][node]
  const int tid = threadIdx.x;
  const int w = tid >> 6;
  const int l = tid & 63;
  const int c = l & 15;
  const int q = l >> 4;
  const int hb = w * 16 + c;            // hidden index owned by this lane
  const int kt_h = hb >> 5;
  const int e_h = hb & 7;
  const int lf_h = 16 * ((hb >> 3) & 3);
  const int blk = blockIdx.x;
  int mtg[2];
  #pragma unroll
  for (int mt = 0; mt < 2; ++mt) mtg[mt] = blk * 2 + mt;

  for (int i = tid; i < 2 * 2 * 64 * 8; i += 256) hF[i] = 0;

  // attn/fc B-frag: col j=0 -> attn_w, j=1 -> fc_w, else 0 (bf16)
  short8 bwA[2];
  #pragma unroll
  for (int kt = 0; kt < 2; ++kt){
    short8 v;
    #pragma unroll
    for (int e = 0; e < 8; ++e){
      int k = q * 8 + e + 32 * kt;
      float f = (c == 0) ? wb[51008 + k] : (c == 1) ? wb[51073 + k] : 0.0f;
      v[e] = (short)f2bf(f);
    }
    bwA[kt] = v;
  }

  float hprev[2][4];

  #pragma unroll
  for (int layer = 0; layer < 2; ++layer){
    if (layer == 1){
      __syncthreads();
      for (int i = tid; i < 2 * 2 * 64 * 8; i += 256) hF[i] = 0;
    }
    #pragma unroll
    for (int mt = 0; mt < 2; ++mt)
      #pragma unroll
      for (int r = 0; r < 4; ++r) hprev[mt][r] = 0.0f;

    const float* bi = wb + 49152 + layer * 384;
    const float* bh = bi + 192;
    float brz = bi[hb] + bh[hb];          // combined r bias
    float bzz = bi[64 + hb] + bh[64 + hb];// combined z bias
    float bin = bi[128 + hb], bhn = bh[128 + hb];

    // B-frags held in registers for the whole layer
    short8 bw[2][3][2];   // [g: ih/hh][slot: jt=w+4*s][kt]
    #pragma unroll
    for (int g = 0; g < 2; ++g)
      #pragma unroll
      for (int s = 0; s < 3; ++s)
        #pragma unroll
        for (int kt = 0; kt < 2; ++kt){
          int jt = w + 4 * s;
          size_t idx = ((((size_t)(layer * 2 + g) * 2 + kt) * 12 + jt) * 64 + l) * 8;
          bw[g][s][kt] = *(const short8*)(wF + idx);
        }

    const unsigned short* xsrc = (layer == 0) ? goutF : h0F;
    short8 xa[4], xb[4];
    #pragma unroll
    for (int mt = 0; mt < 2; ++mt){
      int mc = mtg[mt] < 625 ? mtg[mt] : 624;
      #pragma unroll
      for (int kt = 0; kt < 2; ++kt)
        xa[mt * 2 + kt] = *(const short8*)(xsrc + (((size_t)0 * 625 + mc) * 2 + kt) * 512 + l * 8);
    }
    __syncthreads();

    for (int t = 0; t < SEQ_T; ++t){
      int tn = (t + 1 < SEQ_T) ? t + 1 : t;
      #pragma unroll
      for (int mt = 0; mt < 2; ++mt){
        int mc = mtg[mt] < 625 ? mtg[mt] : 624;
        #pragma unroll
        for (int kt = 0; kt < 2; ++kt)
          xb[mt * 2 + kt] = *(const short8*)(xsrc + (((size_t)tn * 625 + mc) * 2 + kt) * 512 + l * 8);
      }
      short8 ha[4];
      #pragma unroll
      for (int mt = 0; mt < 2; ++mt)
        #pragma unroll
        for (int kt = 0; kt < 2; ++kt)
          ha[mt * 2 + kt] = *(const short8*)&hF[((mt * 2 + kt) * 64 + l) * 8];

      floatx4 acc[2][3][2];
      #pragma unroll
      for (int g = 0; g < 2; ++g)
        #pragma unroll
        for (int s = 0; s < 3; ++s)
          #pragma unroll
          for (int mt = 0; mt < 2; ++mt)
            acc[g][s][mt] = (floatx4){0.f, 0.f, 0.f, 0.f};
      #pragma unroll
      for (int s = 0; s < 3; ++s)
        #pragma unroll
        for (int mt = 0; mt < 2; ++mt)
          #pragma unroll
          for (int kt = 0; kt < 2; ++kt){
            acc[0][s][mt] = __builtin_amdgcn_mfma_f32_16x16x32_bf16(
                xa[mt * 2 + kt], bw[0][s][kt], acc[0][s][mt], 0, 0, 0);
            acc[1][s][mt] = __builtin_amdgcn_mfma_f32_16x16x32_bf16(
                ha[mt * 2 + kt], bw[1][s][kt], acc[1][s][mt], 0, 0, 0);
          }
      // attention dots of h_{t-1} (ha), wave 0 only; scdc[t-1]
      if (layer == 1 && w == 0 && t >= 1){
        floatx4 aA[2];
        #pragma unroll
        for (int mt = 0; mt < 2; ++mt){
          aA[mt] = (floatx4){0.f, 0.f, 0.f, 0.f};
          #pragma unroll
          for (int kt = 0; kt < 2; ++kt)
            aA[mt] = __builtin_amdgcn_mfma_f32_16x16x32_bf16(
                ha[mt * 2 + kt], bwA[kt], aA[mt], 0, 0, 0);
        }
        if (c < 2){
          #pragma unroll
          for (int mt = 0; mt < 2; ++mt)
            #pragma unroll
            for (int r = 0; r < 4; ++r)
              scdc[t - 1][c][mt * 16 + q * 4 + r] = aA[mt][r];
        }
      }
      __syncthreads();   // all waves done reading old hF

      #pragma unroll
      for (int mt = 0; mt < 2; ++mt){
        unsigned short hnb[4];
        #pragma unroll
        for (int r = 0; r < 4; ++r){
          float rr = sigmf(acc[0][0][mt][r] + acc[1][0][mt][r] + brz);
          float zz = sigmf(acc[0][1][mt][r] + acc[1][1][mt][r] + bzz);
          float nn = tanh_fast(acc[0][2][mt][r] + bin + rr * (acc[1][2][mt][r] + bhn));
          float hn = (1.0f - zz) * nn + zz * hprev[mt][r];
          hprev[mt][r] = hn;
          hnb[r] = f2bf(hn);
          hF[((mt * 2 + kt_h) * 64 + (q * 4 + r) + lf_h) * 8 + e_h] = hnb[r];
        }
        if (layer == 0 && mtg[mt] < 625){
          #pragma unroll
          for (int r = 0; r < 4; ++r)
            h0F[(((size_t)t * 625 + mtg[mt]) * 2 + kt_h) * 512
                + ((q * 4 + r) + lf_h) * 8 + e_h] = hnb[r];
        }
      }
      __syncthreads();   // new hF visible before next step's reads

      #pragma unroll
      for (int i = 0; i < 4; ++i) xa[i] = xb[i];
    }
  }

  // final attention dots for h_11 (hF holds layer-1 h_11 now)
  if (w == 0){
    short8 hL[4];
    #pragma unroll
    for (int mt = 0; mt < 2; ++mt)
      #pragma unroll
      for (int kt = 0; kt < 2; ++kt)
        hL[mt * 2 + kt] = *(const short8*)&hF[((mt * 2 + kt) * 64 + l) * 8];
    floatx4 aA[2];
    #pragma unroll
    for (int mt = 0; mt < 2; ++mt){
      aA[mt] = (floatx4){0.f, 0.f, 0.f, 0.f};
      #pragma unroll
      for (int kt = 0; kt < 2; ++kt)
        aA[mt] = __builtin_amdgcn_mfma_f32_16x16x32_bf16(
            hL[mt * 2 + kt], bwA[kt], aA[mt], 0, 0, 0);
    }
    if (c < 2){
      #pragma unroll
      for (int mt = 0; mt < 2; ++mt)
        #pragma unroll
        for (int r = 0; r < 4; ++r)
          scdc[SEQ_T - 1][c][mt * 16 + q * 4 + r] = aA[mt][r];
    }
    // epilogue: softmax over t + fc bias + residual (wave 0, lanes 0..31)
    int gn = blk * 32 + l;
    if (l < 32 && gn < N_NODES){
      float sc[SEQ_T], dc[SEQ_T];
      #pragma unroll
      for (int t = 0; t < SEQ_T; ++t){ sc[t] = scdc[t][0][l]; dc[t] = scdc[t][1][l]; }
      float m = sc[0];
      #pragma unroll
      for (int t = 1; t < SEQ_T; ++t) m = fmaxf(m, sc[t]);
      float den = 0.0f, num = 0.0f;
      #pragma unroll
      for (int t = 0; t < SEQ_T; ++t){
        float p = __expf(sc[t] - m);
        den += p;
        num = fmaf(p, dc[t], num);
      }
      float y = wb[51137] + num / den;
      float last = x[((size_t)(SEQ_T - 1) * N_NODES + gn) * IN_CH];   // x[11][n][0]
      out[gn] = last + y;
    }
  }
}

extern "C" void kernel_launch(void* const* d_in, const int* in_sizes, int n_in,
                              void* d_out, int out_size, void* d_ws, size_t ws_size,
                              hipStream_t stream){
  const float* x = (const float*)d_in[0];   // fp32, (T,N,16)
  const int* ei  = (const int*)d_in[1];     // (2,E)
  char* ws = (char*)d_ws;
  float*          wb    = (float*)(ws);                    // 51138 floats
  unsigned short* wF    = (unsigned short*)(ws + 262144);  // 49152 bf16
  int*            cnt   = (int*)(ws + 393216);             // 10000 (also fill cursor)
  int*            row   = (int*)(ws + 433216);             // 10001
  float*          dis   = (float*)(ws + 473280);           // 10000
  int4*           csr   = (int4*)(ws + 513280);            // 160000 x 16B = 2.56 MB
  unsigned short* goutF = (unsigned short*)(ws + 3073280); // 12*625*1024 bf16 = 15.36 MB
  unsigned short* h0F   = (unsigned short*)(ws + 18433280);// 15.36 MB

  hipMemsetAsync(cnt, 0, N_NODES * sizeof(int), stream);
  k_prep<<<dim3(625, 15), 256, 0, stream>>>(
      (const float*)d_in[2],  (const float*)d_in[3],
      (const float*)d_in[4],  (const float*)d_in[5],
      (const float*)d_in[6],  (const float*)d_in[7],
      (const float*)d_in[8],  (const float*)d_in[9],
      (const float*)d_in[10], (const float*)d_in[11],
      (const float*)d_in[12], (const float*)d_in[13],
      (const float*)d_in[14], (const float*)d_in[15],
      ei, wb, wF, cnt);
  k_scan<<<1, 1024, 0, stream>>>(cnt, row, dis);
  k_fill<<<(N_EDGES + 255) / 256, 256, 0, stream>>>(ei, cnt, dis, csr);
  k_gather_gcn<<<dim3((N_NODES + DCH - 1) / DCH, SEQ_T), 256, 0, stream>>>(
      x, row, csr, dis, wb, goutF);
  k_gru<<<(N_NODES + 31) / 32, 256, 0, stream>>>(goutF, wF, wb, h0F, x, (float*)d_out);
}

// Round 7
// 226.217 us; speedup vs baseline: 1.6509x; 1.6509x over previous
//
#include <hip/hip_runtime.h>
#include <hip/hip_bf16.h>

#define N_NODES 10000
#define SEQ_T 12
#define IN_CH 16
#define HID 64
#define N_EDGES 160000

typedef __attribute__((ext_vector_type(8))) short short8;
typedef __attribute__((ext_vector_type(4))) float floatx4;

// ---- helpers ----
__device__ __forceinline__ float sigmf(float x){ return 1.0f / (1.0f + __expf(-x)); }
__device__ __forceinline__ float tanh_fast(float x){ return 1.0f - 2.0f / (1.0f + __expf(2.0f * x)); }
__device__ __forceinline__ float bf2f(unsigned short u){
  union { unsigned int i; float f; } c; c.i = ((unsigned int)u) << 16; return c.f;
}
__device__ __forceinline__ unsigned short f2bf(float f){
  union { float f; unsigned int u; } c; c.f = f;
  unsigned int u = c.u;
  return (unsigned short)((u + 0x7FFFu + ((u >> 16) & 1u)) >> 16);   // RNE
}

// wb (fp32 param block) float offsets:
//   49152 b_ih0 192 | 49344 b_hh0 192 | 49536 b_ih1 192 | 49728 b_hh1 192
//   49920 gcn_w 1024 | 50944 gcn_b 64
//   51008 attn_w 64 | 51072 attn_b 1 | 51073 fc_w 64 | 51137 fc_b 1
// wF (bf16): 4 matrices (l0ih,l0hh,l1ih,l1hh) x [kt(2)][jt(12)][lane(64)][e(8)]
//   B-frag element = W[j = (lane&15)+16*jt][k = (lane>>4)*8 + e + 32*kt]

// ---- param prep + edge count (cnt pre-zeroed by memset) ----
__global__ void k_prep(const float* __restrict__ gcn_w,
                       const float* __restrict__ gcn_b,
                       const float* __restrict__ wih0,
                       const float* __restrict__ whh0,
                       const float* __restrict__ bih0,
                       const float* __restrict__ bhh0,
                       const float* __restrict__ wih1,
                       const float* __restrict__ whh1,
                       const float* __restrict__ bih1,
                       const float* __restrict__ bhh1,
                       const float* __restrict__ attn_w,
                       const float* __restrict__ attn_b,
                       const float* __restrict__ fc_w,
                       const float* __restrict__ fc_b,
                       const int* __restrict__ ei,
                       float* __restrict__ wb, unsigned short* __restrict__ wF,
                       int* __restrict__ cnt){
  int p = blockIdx.y;
  int i = blockIdx.x * 256 + threadIdx.x;
  if (p == 14){                               // in-degree count over dst
    if (i < N_EDGES) atomicAdd(&cnt[ei[N_EDGES + i]], 1);
    return;
  }
  const float* srcs[14] = {wih0, whh0, wih1, whh1, bih0, bhh0, bih1, bhh1,
                           gcn_w, gcn_b, attn_w, attn_b, fc_w, fc_b};
  const int sizes[14] = {12288,12288,12288,12288,192,192,192,192,1024,64,64,1,64,1};
  const int dsts[14]  = {0,0,0,0,49152,49344,49536,49728,49920,50944,51008,51072,51073,51137};
  if (i >= sizes[p]) return;
  if (p < 4){
    // frag swizzle: i = ((kt*12+jt)*64 + l)*8 + e
    int e = i & 7, l = (i >> 3) & 63, jk = i >> 9;
    int kt = jk / 12, jt = jk - kt * 12;
    int j = (l & 15) + 16 * jt;
    int k = ((l >> 4) * 8) + e + 32 * kt;
    wF[p * 12288 + i] = f2bf(srcs[p][j * 64 + k]);
  } else {
    wb[dsts[p] + i] = srcs[p][i];
  }
}

// ---- exclusive scan -> row offsets; dis = rsqrt(deg); cursor=row (aliases cnt) ----
__global__ __launch_bounds__(1024) void k_scan(int* __restrict__ cnt_cursor,
                                               int* __restrict__ row,
                                               float* __restrict__ dis){
  __shared__ int sums[1024];
  const int CH = 10;
  int tid = threadIdx.x;
  int base = tid * CH;
  int local[CH]; int s = 0;
  #pragma unroll
  for (int i = 0; i < CH; ++i){
    int idx = base + i;
    int v = (idx < N_NODES) ? cnt_cursor[idx] : 0;
    local[i] = s;
    s += v;
    if (idx < N_NODES) dis[idx] = rsqrtf((float)v + 1.0f);
  }
  sums[tid] = s;
  __syncthreads();
  for (int off = 1; off < 1024; off <<= 1){
    int v = (tid >= off) ? sums[tid - off] : 0;
    __syncthreads();
    sums[tid] += v;
    __syncthreads();
  }
  int excl = sums[tid] - s;
  #pragma unroll
  for (int i = 0; i < CH; ++i){
    int idx = base + i;
    if (idx < N_NODES){
      int r = excl + local[i];
      row[idx] = r;
      cnt_cursor[idx] = r;
    }
  }
  if (tid == 1023) row[N_NODES] = sums[1023];
}

// ---- CSR fill: (src, w-bits) packed per edge ----
__global__ void k_fill(const int* __restrict__ ei, int* __restrict__ cursor,
                       const float* __restrict__ dis, int2* __restrict__ csr){
  int e = blockIdx.x * 256 + threadIdx.x;
  if (e >= N_EDGES) return;
  int s = ei[e], d = ei[N_EDGES + e];
  int pos = atomicAdd(&cursor[d], 1);
  csr[pos] = make_int2(s, __float_as_int(dis[s] * dis[d]));
}

// ---- fused gather (t-amortized per-dst) + GCN matmul + relu -> goutF ----
// 16-lane group = one dst; edge list walked ONCE, 12 t-plane loads per edge
// (independent -> 12-wide MLP). Epilogue: LDS exchange + 16->64 GEMM + frag store.
// goutF layout: [t][mt_g(625)][kt(2)][lane(64)][e(8)] bf16,
//   element = act[node = mt_g*16 + (lane&15)][k = kt*32 + (lane>>4)*8 + e]
__global__ __launch_bounds__(256) void k_gather_gcn(
    const float* __restrict__ x, const int* __restrict__ row,
    const int2* __restrict__ csr, const float* __restrict__ dis,
    const float* __restrict__ wb, unsigned short* __restrict__ goutF){
  __shared__ float sm[SEQ_T][16][17];      // [t][grp][ch], +1 pad
  __shared__ float smw[IN_CH * HID];
  __shared__ float smb[HID];
  const int tid = threadIdx.x;
  for (int i = tid; i < IN_CH * HID; i += 256) smw[i] = wb[49920 + i];
  if (tid < HID) smb[tid] = wb[50944 + tid];
  const int g = tid >> 4, ch = tid & 15;
  const int dst = blockIdx.x * 16 + g;
  const bool vd = dst < N_NODES;
  const int dc = vd ? dst : N_NODES - 1;
  float acc[SEQ_T];
  float dd = dis[dc];
  float selfw = dd * dd;
  #pragma unroll
  for (int t = 0; t < SEQ_T; ++t)
    acc[t] = selfw * x[((size_t)t * N_NODES + dc) * IN_CH + ch];
  int r0 = row[dc], r1 = row[dc + 1];
  int2 sw = (r0 < r1) ? csr[r0] : make_int2(0, 0);
  for (int e = r0; e < r1; ++e){
    int2 cur = sw;
    if (e + 1 < r1) sw = csr[e + 1];       // prefetch breaks the chain
    float w = __int_as_float(cur.y);
    const float* xp = x + (size_t)cur.x * IN_CH + ch;
    #pragma unroll
    for (int t = 0; t < SEQ_T; ++t)        // 12 independent loads in flight
      acc[t] = fmaf(w, xp[(size_t)t * N_NODES * IN_CH], acc[t]);
  }
  #pragma unroll
  for (int t = 0; t < SEQ_T; ++t) sm[t][g][ch] = acc[t];
  __syncthreads();
  // epilogue: thread = (dst g, h-quad hq); weights column preloaded to regs
  const int hq = tid & 15;
  if (vd){
    float wreg[16][4];
    #pragma unroll
    for (int f = 0; f < 16; ++f)
      #pragma unroll
      for (int j = 0; j < 4; ++j) wreg[f][j] = smw[f * HID + hq * 4 + j];
    float b0 = smb[hq * 4], b1 = smb[hq * 4 + 1], b2 = smb[hq * 4 + 2], b3 = smb[hq * 4 + 3];
    // store address pieces (h = hq*4+q): kt=hq>>3, lanef=(dst&15)+16*((hq>>1)&3), e0=(hq&1)*4
    size_t sbase = (((size_t)(dst >> 4)) * 2 + (hq >> 3)) * 512
                   + ((dst & 15) + 16 * ((hq >> 1) & 3)) * 8 + (hq & 1) * 4;
    #pragma unroll
    for (int t = 0; t < SEQ_T; ++t){
      float o0 = b0, o1 = b1, o2 = b2, o3 = b3;
      #pragma unroll
      for (int f = 0; f < 16; ++f){
        float v = sm[t][g][f];
        o0 = fmaf(v, wreg[f][0], o0);
        o1 = fmaf(v, wreg[f][1], o1);
        o2 = fmaf(v, wreg[f][2], o2);
        o3 = fmaf(v, wreg[f][3], o3);
      }
      ushort4 ov;
      ov.x = f2bf(fmaxf(o0, 0.0f));
      ov.y = f2bf(fmaxf(o1, 0.0f));
      ov.z = f2bf(fmaxf(o2, 0.0f));
      ov.w = f2bf(fmaxf(o3, 0.0f));
      *(ushort4*)(goutF + (size_t)t * 625 * 1024 + sbase) = ov;
    }
  }
}

// ---- fused 2-layer GRU on MFMA + attention/FC/residual epilogue. ----
// block = 32 nodes (2 m-tiles), 4 waves; wave w owns j-tiles {w, w+4, w+8}.
__global__ __launch_bounds__(256, 1) void k_gru(
    const unsigned short* __restrict__ goutF, const unsigned short* __restrict__ wF,
    const float* __restrict__ wb, unsigned short* __restrict__ h0F,
    const float* __restrict__ x, float* __restrict__ out){
  __shared__ unsigned short hF[2 * 2 * 64 * 8];   // [mt][kt][lane][e], bf16
  __shared__ float scdc[SEQ_T][2][32];            // [t][sc/dc][node]
  const int tid = threadIdx.x;
  const int w = tid >> 6;
  const int l = tid & 63;
  const int c = l & 15;
  const int q = l >> 4;
  const int hb = w * 16 + c;            // hidden index owned by this lane
  const int kt_h = hb >> 5;
  const int e_h = hb & 7;
  const int lf_h = 16 * ((hb >> 3) & 3);
  const int blk = blockIdx.x;
  int mtg[2];
  #pragma unroll
  for (int mt = 0; mt < 2; ++mt) mtg[mt] = blk * 2 + mt;

  for (int i = tid; i < 2 * 2 * 64 * 8; i += 256) hF[i] = 0;

  // attn/fc B-frag: col j=0 -> attn_w, j=1 -> fc_w, else 0 (bf16)
  short8 bwA[2];
  #pragma unroll
  for (int kt = 0; kt < 2; ++kt){
    short8 v;
    #pragma unroll
    for (int e = 0; e < 8; ++e){
      int k = q * 8 + e + 32 * kt;
      float f = (c == 0) ? wb[51008 + k] : (c == 1) ? wb[51073 + k] : 0.0f;
      v[e] = (short)f2bf(f);
    }
    bwA[kt] = v;
  }

  float hprev[2][4];

  #pragma unroll
  for (int layer = 0; layer < 2; ++layer){
    if (layer == 1){
      __syncthreads();
      for (int i = tid; i < 2 * 2 * 64 * 8; i += 256) hF[i] = 0;
    }
    #pragma unroll
    for (int mt = 0; mt < 2; ++mt)
      #pragma unroll
      for (int r = 0; r < 4; ++r) hprev[mt][r] = 0.0f;

    const float* bi = wb + 49152 + layer * 384;
    const float* bh = bi + 192;
    float brz = bi[hb] + bh[hb];          // combined r bias
    float bzz = bi[64 + hb] + bh[64 + hb];// combined z bias
    float bin = bi[128 + hb], bhn = bh[128 + hb];

    // B-frags held in registers for the whole layer
    short8 bw[2][3][2];   // [g: ih/hh][slot: jt=w+4*s][kt]
    #pragma unroll
    for (int g = 0; g < 2; ++g)
      #pragma unroll
      for (int s = 0; s < 3; ++s)
        #pragma unroll
        for (int kt = 0; kt < 2; ++kt){
          int jt = w + 4 * s;
          size_t idx = ((((size_t)(layer * 2 + g) * 2 + kt) * 12 + jt) * 64 + l) * 8;
          bw[g][s][kt] = *(const short8*)(wF + idx);
        }

    const unsigned short* xsrc = (layer == 0) ? goutF : h0F;
    short8 xa[4], xb[4];
    #pragma unroll
    for (int mt = 0; mt < 2; ++mt){
      int mc = mtg[mt] < 625 ? mtg[mt] : 624;
      #pragma unroll
      for (int kt = 0; kt < 2; ++kt)
        xa[mt * 2 + kt] = *(const short8*)(xsrc + (((size_t)0 * 625 + mc) * 2 + kt) * 512 + l * 8);
    }
    __syncthreads();

    for (int t = 0; t < SEQ_T; ++t){
      int tn = (t + 1 < SEQ_T) ? t + 1 : t;
      #pragma unroll
      for (int mt = 0; mt < 2; ++mt){
        int mc = mtg[mt] < 625 ? mtg[mt] : 624;
        #pragma unroll
        for (int kt = 0; kt < 2; ++kt)
          xb[mt * 2 + kt] = *(const short8*)(xsrc + (((size_t)tn * 625 + mc) * 2 + kt) * 512 + l * 8);
      }
      short8 ha[4];
      #pragma unroll
      for (int mt = 0; mt < 2; ++mt)
        #pragma unroll
        for (int kt = 0; kt < 2; ++kt)
          ha[mt * 2 + kt] = *(const short8*)&hF[((mt * 2 + kt) * 64 + l) * 8];

      floatx4 acc[2][3][2];
      #pragma unroll
      for (int g = 0; g < 2; ++g)
        #pragma unroll
        for (int s = 0; s < 3; ++s)
          #pragma unroll
          for (int mt = 0; mt < 2; ++mt)
            acc[g][s][mt] = (floatx4){0.f, 0.f, 0.f, 0.f};
      #pragma unroll
      for (int s = 0; s < 3; ++s)
        #pragma unroll
        for (int mt = 0; mt < 2; ++mt)
          #pragma unroll
          for (int kt = 0; kt < 2; ++kt){
            acc[0][s][mt] = __builtin_amdgcn_mfma_f32_16x16x32_bf16(
                xa[mt * 2 + kt], bw[0][s][kt], acc[0][s][mt], 0, 0, 0);
            acc[1][s][mt] = __builtin_amdgcn_mfma_f32_16x16x32_bf16(
                ha[mt * 2 + kt], bw[1][s][kt], acc[1][s][mt], 0, 0, 0);
          }
      // attention dots of h_{t-1} (ha), wave 0 only; scdc[t-1]
      if (layer == 1 && w == 0 && t >= 1){
        floatx4 aA[2];
        #pragma unroll
        for (int mt = 0; mt < 2; ++mt){
          aA[mt] = (floatx4){0.f, 0.f, 0.f, 0.f};
          #pragma unroll
          for (int kt = 0; kt < 2; ++kt)
            aA[mt] = __builtin_amdgcn_mfma_f32_16x16x32_bf16(
                ha[mt * 2 + kt], bwA[kt], aA[mt], 0, 0, 0);
        }
        if (c < 2){
          #pragma unroll
          for (int mt = 0; mt < 2; ++mt)
            #pragma unroll
            for (int r = 0; r < 4; ++r)
              scdc[t - 1][c][mt * 16 + q * 4 + r] = aA[mt][r];
        }
      }
      __syncthreads();   // all waves done reading old hF

      #pragma unroll
      for (int mt = 0; mt < 2; ++mt){
        unsigned short hnb[4];
        #pragma unroll
        for (int r = 0; r < 4; ++r){
          float rr = sigmf(acc[0][0][mt][r] + acc[1][0][mt][r] + brz);
          float zz = sigmf(acc[0][1][mt][r] + acc[1][1][mt][r] + bzz);
          float nn = tanh_fast(acc[0][2][mt][r] + bin + rr * (acc[1][2][mt][r] + bhn));
          float hn = (1.0f - zz) * nn + zz * hprev[mt][r];
          hprev[mt][r] = hn;
          hnb[r] = f2bf(hn);
          hF[((mt * 2 + kt_h) * 64 + (q * 4 + r) + lf_h) * 8 + e_h] = hnb[r];
        }
        if (layer == 0 && mtg[mt] < 625){
          #pragma unroll
          for (int r = 0; r < 4; ++r)
            h0F[(((size_t)t * 625 + mtg[mt]) * 2 + kt_h) * 512
                + ((q * 4 + r) + lf_h) * 8 + e_h] = hnb[r];
        }
      }
      __syncthreads();   // new hF visible before next step's reads

      #pragma unroll
      for (int i = 0; i < 4; ++i) xa[i] = xb[i];
    }
  }

  // final attention dots for h_11 (hF holds layer-1 h_11 now)
  if (w == 0){
    short8 hL[4];
    #pragma unroll
    for (int mt = 0; mt < 2; ++mt)
      #pragma unroll
      for (int kt = 0; kt < 2; ++kt)
        hL[mt * 2 + kt] = *(const short8*)&hF[((mt * 2 + kt) * 64 + l) * 8];
    floatx4 aA[2];
    #pragma unroll
    for (int mt = 0; mt < 2; ++mt){
      aA[mt] = (floatx4){0.f, 0.f, 0.f, 0.f};
      #pragma unroll
      for (int kt = 0; kt < 2; ++kt)
        aA[mt] = __builtin_amdgcn_mfma_f32_16x16x32_bf16(
            hL[mt * 2 + kt], bwA[kt], aA[mt], 0, 0, 0);
    }
    if (c < 2){
      #pragma unroll
      for (int mt = 0; mt < 2; ++mt)
        #pragma unroll
        for (int r = 0; r < 4; ++r)
          scdc[SEQ_T - 1][c][mt * 16 + q * 4 + r] = aA[mt][r];
    }
    // epilogue: softmax over t + fc bias + residual (wave 0, lanes 0..31)
    int gn = blk * 32 + l;
    if (l < 32 && gn < N_NODES){
      float sc[SEQ_T], dc[SEQ_T];
      #pragma unroll
      for (int t = 0; t < SEQ_T; ++t){ sc[t] = scdc[t][0][l]; dc[t] = scdc[t][1][l]; }
      float m = sc[0];
      #pragma unroll
      for (int t = 1; t < SEQ_T; ++t) m = fmaxf(m, sc[t]);
      float den = 0.0f, num = 0.0f;
      #pragma unroll
      for (int t = 0; t < SEQ_T; ++t){
        float p = __expf(sc[t] - m);
        den += p;
        num = fmaf(p, dc[t], num);
      }
      float y = wb[51137] + num / den;
      float last = x[((size_t)(SEQ_T - 1) * N_NODES + gn) * IN_CH];   // x[11][n][0]
      out[gn] = last + y;
    }
  }
}

extern "C" void kernel_launch(void* const* d_in, const int* in_sizes, int n_in,
                              void* d_out, int out_size, void* d_ws, size_t ws_size,
                              hipStream_t stream){
  const float* x = (const float*)d_in[0];   // fp32, (T,N,16)
  const int* ei  = (const int*)d_in[1];     // (2,E)
  char* ws = (char*)d_ws;
  float*          wb    = (float*)(ws);                    // 51138 floats
  unsigned short* wF    = (unsigned short*)(ws + 262144);  // 49152 bf16
  int*            cnt   = (int*)(ws + 393216);             // 10000 (also fill cursor)
  int*            row   = (int*)(ws + 433216);             // 10001
  float*          dis   = (float*)(ws + 473280);           // 10000
  int2*           csr   = (int2*)(ws + 513280);            // 160000 x 8B = 1.28 MB
  unsigned short* goutF = (unsigned short*)(ws + 1793280); // 12*625*1024 bf16 = 15.36 MB
  unsigned short* h0F   = (unsigned short*)(ws + 17153280);// 15.36 MB

  hipMemsetAsync(cnt, 0, N_NODES * sizeof(int), stream);
  k_prep<<<dim3(625, 15), 256, 0, stream>>>(
      (const float*)d_in[2],  (const float*)d_in[3],
      (const float*)d_in[4],  (const float*)d_in[5],
      (const float*)d_in[6],  (const float*)d_in[7],
      (const float*)d_in[8],  (const float*)d_in[9],
      (const float*)d_in[10], (const float*)d_in[11],
      (const float*)d_in[12], (const float*)d_in[13],
      (const float*)d_in[14], (const float*)d_in[15],
      ei, wb, wF, cnt);
  k_scan<<<1, 1024, 0, stream>>>(cnt, row, dis);
  k_fill<<<(N_EDGES + 255) / 256, 256, 0, stream>>>(ei, cnt, dis, csr);
  k_gather_gcn<<<(N_NODES + 15) / 16, 256, 0, stream>>>(x, row, csr, dis, wb, goutF);
  k_gru<<<(N_NODES + 31) / 32, 256, 0, stream>>>(goutF, wF, wb, h0F, x, (float*)d_out);
}

// Round 8
// 201.527 us; speedup vs baseline: 1.8532x; 1.1225x over previous
//
#include <hip/hip_runtime.h>
#include <hip/hip_bf16.h>

#define N_NODES 10000
#define SEQ_T 12
#define IN_CH 16
#define HID 64
#define N_EDGES 160000

typedef __attribute__((ext_vector_type(8))) short short8;
typedef __attribute__((ext_vector_type(4))) float floatx4;

// ---- helpers ----
__device__ __forceinline__ float sigmf(float x){ return 1.0f / (1.0f + __expf(-x)); }
__device__ __forceinline__ float tanh_fast(float x){ return 1.0f - 2.0f / (1.0f + __expf(2.0f * x)); }
__device__ __forceinline__ unsigned short f2bf(float f){
  union { float f; unsigned int u; } c; c.f = f;
  unsigned int u = c.u;
  return (unsigned short)((u + 0x7FFFu + ((u >> 16) & 1u)) >> 16);   // RNE
}

// wb (fp32 param block) float offsets:
//   49152 b_ih0 192 | 49344 b_hh0 192 | 49536 b_ih1 192 | 49728 b_hh1 192
//   49920 gcn_w 1024 | 50944 gcn_b 64
//   51008 attn_w 64 | 51072 attn_b 1 | 51073 fc_w 64 | 51137 fc_b 1
// wF (bf16): 4 matrices (l0ih,l0hh,l1ih,l1hh) x [kt(2)][jt(12)][lane(64)][e(8)]
//   B-frag element = W[j = (lane&15)+16*jt][k = (lane>>4)*8 + e + 32*kt]

// ---- param prep + edge count (cnt pre-zeroed by memset) ----
__global__ void k_prep(const float* __restrict__ gcn_w,
                       const float* __restrict__ gcn_b,
                       const float* __restrict__ wih0,
                       const float* __restrict__ whh0,
                       const float* __restrict__ bih0,
                       const float* __restrict__ bhh0,
                       const float* __restrict__ wih1,
                       const float* __restrict__ whh1,
                       const float* __restrict__ bih1,
                       const float* __restrict__ bhh1,
                       const float* __restrict__ attn_w,
                       const float* __restrict__ attn_b,
                       const float* __restrict__ fc_w,
                       const float* __restrict__ fc_b,
                       const int* __restrict__ ei,
                       float* __restrict__ wb, unsigned short* __restrict__ wF,
                       int* __restrict__ cnt){
  int p = blockIdx.y;
  int i = blockIdx.x * 256 + threadIdx.x;
  if (p == 14){                               // in-degree count over dst
    if (i < N_EDGES) atomicAdd(&cnt[ei[N_EDGES + i]], 1);
    return;
  }
  const float* srcs[14] = {wih0, whh0, wih1, whh1, bih0, bhh0, bih1, bhh1,
                           gcn_w, gcn_b, attn_w, attn_b, fc_w, fc_b};
  const int sizes[14] = {12288,12288,12288,12288,192,192,192,192,1024,64,64,1,64,1};
  const int dsts[14]  = {0,0,0,0,49152,49344,49536,49728,49920,50944,51008,51072,51073,51137};
  if (i >= sizes[p]) return;
  if (p < 4){
    // frag swizzle: i = ((kt*12+jt)*64 + l)*8 + e
    int e = i & 7, l = (i >> 3) & 63, jk = i >> 9;
    int kt = jk / 12, jt = jk - kt * 12;
    int j = (l & 15) + 16 * jt;
    int k = ((l >> 4) * 8) + e + 32 * kt;
    wF[p * 12288 + i] = f2bf(srcs[p][j * 64 + k]);
  } else {
    wb[dsts[p] + i] = srcs[p][i];
  }
}

// ---- exclusive scan -> row offsets; dis = rsqrt(deg); cursor=row (aliases cnt) ----
__global__ __launch_bounds__(1024) void k_scan(int* __restrict__ cnt_cursor,
                                               int* __restrict__ row,
                                               float* __restrict__ dis){
  __shared__ int sums[1024];
  const int CH = 10;
  int tid = threadIdx.x;
  int base = tid * CH;
  int local[CH]; int s = 0;
  #pragma unroll
  for (int i = 0; i < CH; ++i){
    int idx = base + i;
    int v = (idx < N_NODES) ? cnt_cursor[idx] : 0;
    local[i] = s;
    s += v;
    if (idx < N_NODES) dis[idx] = rsqrtf((float)v + 1.0f);
  }
  sums[tid] = s;
  __syncthreads();
  for (int off = 1; off < 1024; off <<= 1){
    int v = (tid >= off) ? sums[tid - off] : 0;
    __syncthreads();
    sums[tid] += v;
    __syncthreads();
  }
  int excl = sums[tid] - s;
  #pragma unroll
  for (int i = 0; i < CH; ++i){
    int idx = base + i;
    if (idx < N_NODES){
      int r = excl + local[i];
      row[idx] = r;
      cnt_cursor[idx] = r;
    }
  }
  if (tid == 1023) row[N_NODES] = sums[1023];
}

// ---- CSR fill: (src, w-bits) packed per edge ----
__global__ void k_fill(const int* __restrict__ ei, int* __restrict__ cursor,
                       const float* __restrict__ dis, int2* __restrict__ csr){
  int e = blockIdx.x * 256 + threadIdx.x;
  if (e >= N_EDGES) return;
  int s = ei[e], d = ei[N_EDGES + e];
  int pos = atomicAdd(&cursor[d], 1);
  csr[pos] = make_int2(s, __float_as_int(dis[s] * dis[d]));
}

// ---- fused gather + GCN matmul + relu -> goutF ----
// 16-lane group = one dst. Edge list walked once in chunks of 16: lane ch does a
// COALESCED csr load of edge base+ch -> LDS stage -> broadcast reads, so the 12
// t-plane x loads sit behind an LDS read (~30cyc), not a global csr load (~300).
// goutF layout: [t][mt(625)][kt(2)][lane(64)][e(8)] bf16,
//   element = act[node = mt*16 + (lane&15)][k = kt*32 + (lane>>4)*8 + e]
__global__ __launch_bounds__(256) void k_gather_gcn(
    const float* __restrict__ x, const int* __restrict__ row,
    const int2* __restrict__ csr, const float* __restrict__ dis,
    const float* __restrict__ wb, unsigned short* __restrict__ goutF){
  __shared__ float sm[SEQ_T][16][17];      // [t][grp][ch], +1 pad
  __shared__ float smw[IN_CH * HID];
  __shared__ float smb[HID];
  __shared__ int2 eLDS[16][16];            // [grp][slot] staged edges
  const int tid = threadIdx.x;
  for (int i = tid; i < IN_CH * HID; i += 256) smw[i] = wb[49920 + i];
  if (tid < HID) smb[tid] = wb[50944 + tid];
  const int g = tid >> 4, ch = tid & 15;
  const int dst = blockIdx.x * 16 + g;     // 625*16 == 10000 exact
  float acc[SEQ_T];
  float dd = dis[dst];
  float selfw = dd * dd;
  #pragma unroll
  for (int t = 0; t < SEQ_T; ++t)
    acc[t] = selfw * x[((size_t)t * N_NODES + dst) * IN_CH + ch];
  int r0 = row[dst], r1 = row[dst + 1];
  for (int base = r0; base < r1; base += 16){
    int ep = base + ch;
    eLDS[g][ch] = (ep < r1) ? csr[ep] : make_int2(0, 0);   // coalesced within group
    int cnt = r1 - base; if (cnt > 16) cnt = 16;
    // same-wave LDS write->read: compiler inserts lgkmcnt wait, no barrier needed
    #pragma unroll 4
    for (int j = 0; j < cnt; ++j){
      int2 e = eLDS[g][j];                 // broadcast within group
      float wgt = __int_as_float(e.y);
      const float* xp = x + (size_t)e.x * IN_CH + ch;
      #pragma unroll
      for (int t = 0; t < SEQ_T; ++t)      // 12 independent loads in flight
        acc[t] = fmaf(wgt, xp[(size_t)t * N_NODES * IN_CH], acc[t]);
    }
  }
  #pragma unroll
  for (int t = 0; t < SEQ_T; ++t) sm[t][g][ch] = acc[t];
  __syncthreads();
  // epilogue: thread = (dst g, h-quad hq); weight columns in registers
  const int hq = tid & 15;
  {
    float wreg[16][4];
    #pragma unroll
    for (int f = 0; f < 16; ++f)
      #pragma unroll
      for (int j = 0; j < 4; ++j) wreg[f][j] = smw[f * HID + hq * 4 + j];
    float b0 = smb[hq * 4], b1 = smb[hq * 4 + 1], b2 = smb[hq * 4 + 2], b3 = smb[hq * 4 + 3];
    size_t sbase = (((size_t)(dst >> 4)) * 2 + (hq >> 3)) * 512
                   + ((dst & 15) + 16 * ((hq >> 1) & 3)) * 8 + (hq & 1) * 4;
    #pragma unroll
    for (int t = 0; t < SEQ_T; ++t){
      float o0 = b0, o1 = b1, o2 = b2, o3 = b3;
      #pragma unroll
      for (int f = 0; f < 16; ++f){
        float v = sm[t][g][f];
        o0 = fmaf(v, wreg[f][0], o0);
        o1 = fmaf(v, wreg[f][1], o1);
        o2 = fmaf(v, wreg[f][2], o2);
        o3 = fmaf(v, wreg[f][3], o3);
      }
      ushort4 ov;
      ov.x = f2bf(fmaxf(o0, 0.0f));
      ov.y = f2bf(fmaxf(o1, 0.0f));
      ov.z = f2bf(fmaxf(o2, 0.0f));
      ov.w = f2bf(fmaxf(o3, 0.0f));
      *(ushort4*)(goutF + (size_t)t * 625 * 1024 + sbase) = ov;
    }
  }
}

// ---- fused 2-layer GRU, fully LDS-resident, + attention/FC/residual epilogue ----
// block = 16 nodes (1 m-tile), 4 waves; wave w owns j-tiles {w, w+4, w+8}.
// Layer0 h-history lives in LDS hL0[t+1] (hL0[0]=zeros) -> layer1 reads it from
// LDS; h1 double-buffered. ONE barrier per step, zero global traffic in the loop.
__global__ __launch_bounds__(256) void k_gru(
    const unsigned short* __restrict__ goutF, const unsigned short* __restrict__ wF,
    const float* __restrict__ wb, const float* __restrict__ x,
    float* __restrict__ out){
  __shared__ unsigned short hL0[SEQ_T + 1][2 * 64 * 8];  // [t+1][kt][lane][e]
  __shared__ unsigned short h1[2][2 * 64 * 8];
  __shared__ float scdc[SEQ_T][2][16];                   // [t][sc/dc][node]
  const int tid = threadIdx.x;
  const int w = tid >> 6;
  const int l = tid & 63;
  const int c = l & 15;
  const int q = l >> 4;
  const int hb = w * 16 + c;            // hidden index owned by this lane
  const int kt_h = hb >> 5;
  const int e_h = hb & 7;
  const int lf_h = 16 * ((hb >> 3) & 3);
  const int blk = blockIdx.x;           // == m-tile, 625 blocks exact

  for (int i = tid; i < 1024; i += 256){ hL0[0][i] = 0; h1[0][i] = 0; }

  // attn/fc B-frag: col j=0 -> attn_w, j=1 -> fc_w, else 0 (bf16)
  short8 bwA[2];
  #pragma unroll
  for (int kt = 0; kt < 2; ++kt){
    short8 v;
    #pragma unroll
    for (int e = 0; e < 8; ++e){
      int k = q * 8 + e + 32 * kt;
      float f = (c == 0) ? wb[51008 + k] : (c == 1) ? wb[51073 + k] : 0.0f;
      v[e] = (short)f2bf(f);
    }
    bwA[kt] = v;
  }

  // ---------------- layer 0 (x from goutF global, h history -> LDS) ----------
  {
    const float* bi = wb + 49152;
    const float* bh = bi + 192;
    float brz = bi[hb] + bh[hb];
    float bzz = bi[64 + hb] + bh[64 + hb];
    float bin = bi[128 + hb], bhn = bh[128 + hb];
    short8 bw[2][3][2];
    #pragma unroll
    for (int g = 0; g < 2; ++g)
      #pragma unroll
      for (int s = 0; s < 3; ++s)
        #pragma unroll
        for (int kt = 0; kt < 2; ++kt){
          int jt = w + 4 * s;
          size_t idx = ((((size_t)g * 2 + kt) * 12 + jt) * 64 + l) * 8;
          bw[g][s][kt] = *(const short8*)(wF + idx);
        }
    float hp[4] = {0.f, 0.f, 0.f, 0.f};
    short8 xa[2], xb[2];
    #pragma unroll
    for (int kt = 0; kt < 2; ++kt)
      xa[kt] = *(const short8*)(goutF + (((size_t)0 * 625 + blk) * 2 + kt) * 512 + l * 8);
    __syncthreads();    // zeros of hL0[0]/h1[0] visible
    for (int t = 0; t < SEQ_T; ++t){
      int tn = (t + 1 < SEQ_T) ? t + 1 : t;
      #pragma unroll
      for (int kt = 0; kt < 2; ++kt)
        xb[kt] = *(const short8*)(goutF + (((size_t)tn * 625 + blk) * 2 + kt) * 512 + l * 8);
      short8 ha[2];
      #pragma unroll
      for (int kt = 0; kt < 2; ++kt)
        ha[kt] = *(const short8*)&hL0[t][(kt * 64 + l) * 8];
      floatx4 acc[2][3];
      #pragma unroll
      for (int g = 0; g < 2; ++g)
        #pragma unroll
        for (int s = 0; s < 3; ++s) acc[g][s] = (floatx4){0.f, 0.f, 0.f, 0.f};
      #pragma unroll
      for (int s = 0; s < 3; ++s)
        #pragma unroll
        for (int kt = 0; kt < 2; ++kt){
          acc[0][s] = __builtin_amdgcn_mfma_f32_16x16x32_bf16(xa[kt], bw[0][s][kt], acc[0][s], 0, 0, 0);
          acc[1][s] = __builtin_amdgcn_mfma_f32_16x16x32_bf16(ha[kt], bw[1][s][kt], acc[1][s], 0, 0, 0);
        }
      #pragma unroll
      for (int r = 0; r < 4; ++r){
        float rr = sigmf(acc[0][0][r] + acc[1][0][r] + brz);
        float zz = sigmf(acc[0][1][r] + acc[1][1][r] + bzz);
        float nn = tanh_fast(acc[0][2][r] + bin + rr * (acc[1][2][r] + bhn));
        float hn = (1.0f - zz) * nn + zz * hp[r];
        hp[r] = hn;
        hL0[t + 1][(kt_h * 64 + (q * 4 + r) + lf_h) * 8 + e_h] = f2bf(hn);
      }
      __syncthreads();  // hL0[t+1] visible for next step / layer1
      xa[0] = xb[0]; xa[1] = xb[1];
    }
  }

  // ---------------- layer 1 (x from hL0 LDS, h1 double-buffered) -------------
  {
    const float* bi = wb + 49536;
    const float* bh = bi + 192;
    float brz = bi[hb] + bh[hb];
    float bzz = bi[64 + hb] + bh[64 + hb];
    float bin = bi[128 + hb], bhn = bh[128 + hb];
    short8 bw[2][3][2];
    #pragma unroll
    for (int g = 0; g < 2; ++g)
      #pragma unroll
      for (int s = 0; s < 3; ++s)
        #pragma unroll
        for (int kt = 0; kt < 2; ++kt){
          int jt = w + 4 * s;
          size_t idx = ((((size_t)(2 + g) * 2 + kt) * 12 + jt) * 64 + l) * 8;
          bw[g][s][kt] = *(const short8*)(wF + idx);
        }
    float hp[4] = {0.f, 0.f, 0.f, 0.f};
    for (int t = 0; t < SEQ_T; ++t){
      int pr = t & 1;                       // read buffer (h_{t-1}); write 1-pr
      short8 xa[2], ha[2];
      #pragma unroll
      for (int kt = 0; kt < 2; ++kt){
        xa[kt] = *(const short8*)&hL0[t + 1][(kt * 64 + l) * 8];
        ha[kt] = *(const short8*)&h1[pr][(kt * 64 + l) * 8];
      }
      floatx4 acc[2][3];
      #pragma unroll
      for (int g = 0; g < 2; ++g)
        #pragma unroll
        for (int s = 0; s < 3; ++s) acc[g][s] = (floatx4){0.f, 0.f, 0.f, 0.f};
      #pragma unroll
      for (int s = 0; s < 3; ++s)
        #pragma unroll
        for (int kt = 0; kt < 2; ++kt){
          acc[0][s] = __builtin_amdgcn_mfma_f32_16x16x32_bf16(xa[kt], bw[0][s][kt], acc[0][s], 0, 0, 0);
          acc[1][s] = __builtin_amdgcn_mfma_f32_16x16x32_bf16(ha[kt], bw[1][s][kt], acc[1][s], 0, 0, 0);
        }
      if (w == 0 && t >= 1){                // attention dots of h_{t-1}
        floatx4 aA = (floatx4){0.f, 0.f, 0.f, 0.f};
        #pragma unroll
        for (int kt = 0; kt < 2; ++kt)
          aA = __builtin_amdgcn_mfma_f32_16x16x32_bf16(ha[kt], bwA[kt], aA, 0, 0, 0);
        if (c < 2){
          #pragma unroll
          for (int r = 0; r < 4; ++r) scdc[t - 1][c][q * 4 + r] = aA[r];
        }
      }
      #pragma unroll
      for (int r = 0; r < 4; ++r){
        float rr = sigmf(acc[0][0][r] + acc[1][0][r] + brz);
        float zz = sigmf(acc[0][1][r] + acc[1][1][r] + bzz);
        float nn = tanh_fast(acc[0][2][r] + bin + rr * (acc[1][2][r] + bhn));
        float hn = (1.0f - zz) * nn + zz * hp[r];
        hp[r] = hn;
        h1[1 - pr][(kt_h * 64 + (q * 4 + r) + lf_h) * 8 + e_h] = f2bf(hn);
      }
      __syncthreads();  // h1[1-pr] visible for next step's read
    }
  }

  // final attention dots for h_11 (written to h1[0] at t=11) + epilogue
  if (w == 0){
    short8 hL[2];
    #pragma unroll
    for (int kt = 0; kt < 2; ++kt)
      hL[kt] = *(const short8*)&h1[0][(kt * 64 + l) * 8];
    floatx4 aA = (floatx4){0.f, 0.f, 0.f, 0.f};
    #pragma unroll
    for (int kt = 0; kt < 2; ++kt)
      aA = __builtin_amdgcn_mfma_f32_16x16x32_bf16(hL[kt], bwA[kt], aA, 0, 0, 0);
    if (c < 2){
      #pragma unroll
      for (int r = 0; r < 4; ++r) scdc[SEQ_T - 1][c][q * 4 + r] = aA[r];
    }
    int gn = blk * 16 + l;
    if (l < 16){
      float sc[SEQ_T], dc[SEQ_T];
      #pragma unroll
      for (int t = 0; t < SEQ_T; ++t){ sc[t] = scdc[t][0][l]; dc[t] = scdc[t][1][l]; }
      float m = sc[0];
      #pragma unroll
      for (int t = 1; t < SEQ_T; ++t) m = fmaxf(m, sc[t]);
      float den = 0.0f, num = 0.0f;
      #pragma unroll
      for (int t = 0; t < SEQ_T; ++t){
        float p = __expf(sc[t] - m);
        den += p;
        num = fmaf(p, dc[t], num);
      }
      float y = wb[51137] + num / den;
      float last = x[((size_t)(SEQ_T - 1) * N_NODES + gn) * IN_CH];   // x[11][n][0]
      out[gn] = last + y;
    }
  }
}

extern "C" void kernel_launch(void* const* d_in, const int* in_sizes, int n_in,
                              void* d_out, int out_size, void* d_ws, size_t ws_size,
                              hipStream_t stream){
  const float* x = (const float*)d_in[0];   // fp32, (T,N,16)
  const int* ei  = (const int*)d_in[1];     // (2,E)
  char* ws = (char*)d_ws;
  float*          wb    = (float*)(ws);                    // 51138 floats
  unsigned short* wF    = (unsigned short*)(ws + 262144);  // 49152 bf16
  int*            cnt   = (int*)(ws + 393216);             // 10000 (also fill cursor)
  int*            row   = (int*)(ws + 433216);             // 10001
  float*          dis   = (float*)(ws + 473280);           // 10000
  int2*           csr   = (int2*)(ws + 513280);            // 160000 x 8B = 1.28 MB
  unsigned short* goutF = (unsigned short*)(ws + 1793280); // 12*625*1024 bf16 = 15.36 MB

  hipMemsetAsync(cnt, 0, N_NODES * sizeof(int), stream);
  k_prep<<<dim3(625, 15), 256, 0, stream>>>(
      (const float*)d_in[2],  (const float*)d_in[3],
      (const float*)d_in[4],  (const float*)d_in[5],
      (const float*)d_in[6],  (const float*)d_in[7],
      (const float*)d_in[8],  (const float*)d_in[9],
      (const float*)d_in[10], (const float*)d_in[11],
      (const float*)d_in[12], (const float*)d_in[13],
      (const float*)d_in[14], (const float*)d_in[15],
      ei, wb, wF, cnt);
  k_scan<<<1, 1024, 0, stream>>>(cnt, row, dis);
  k_fill<<<(N_EDGES + 255) / 256, 256, 0, stream>>>(ei, cnt, dis, csr);
  k_gather_gcn<<<625, 256, 0, stream>>>(x, row, csr, dis, wb, goutF);
  k_gru<<<625, 256, 0, stream>>>(goutF, wF, wb, x, (float*)d_out);
}